// Round 1
// baseline (284.358 us; speedup 1.0000x reference)
//
#include <hip/hip_runtime.h>

// RRSVM: per (b,c,h,w) take 3x3 zero-padded window, stable-sort descending,
// out = sum_r v_sorted[r] * s[c,r]; also emit argsort indices (rank order),
// written as float-encoded ints (harness reads whole d_out as float32).
//
// Shapes: x [16,128,56,56] f32, s [128,3,3] f32.
// d_out = out (6422528 f32) ++ indices (57802752 "f32"-encoded ints).

#define B_ 16
#define C_ 128
#define H_ 56
#define W_ 56
#define NOUT (B_*C_*H_*W_)   // 6422528
#define BLK 256

// Compare-exchange, descending, adjacent-only & strict => stable.
#define CE(i, j) do {                                   \
    float vi = v[(i)], vj = v[(j)];                     \
    float ii = id[(i)], ij = id[(j)];                   \
    bool sw = vj > vi;                                  \
    v[(i)]  = sw ? vj : vi;  v[(j)]  = sw ? vi : vj;    \
    id[(i)] = sw ? ij : ii;  id[(j)] = sw ? ii : ij;    \
} while (0)

__global__ __launch_bounds__(BLK) void rrsvm_kernel(
    const float* __restrict__ x, const float* __restrict__ s,
    float* __restrict__ out, float* __restrict__ idxout)
{
    __shared__ float lds[BLK * 9];   // 9216 B: staged index tile for coalesced writes

    const int tid = threadIdx.x;
    const int gid = blockIdx.x * BLK + tid;      // flat (b,c,h,w), same layout as x

    const int w  = gid % W_;
    const int t  = gid / W_;
    const int h  = t % H_;
    const int bc = t / H_;          // b*C + c
    const int c  = bc % C_;

    // ---- gather 3x3 window (zero pad) ----
    const float* xp = x + gid;
    float v[9];
    float id[9];
    #pragma unroll
    for (int dy = 0; dy < 3; ++dy) {
        #pragma unroll
        for (int dx = 0; dx < 3; ++dx) {
            const int k  = dy * 3 + dx;
            const int hh = h + dy - 1;
            const int ww = w + dx - 1;
            float val = 0.0f;
            if ((unsigned)hh < (unsigned)H_ && (unsigned)ww < (unsigned)W_)
                val = xp[(dy - 1) * W_ + (dx - 1)];
            v[k]  = val;
            id[k] = (float)k;
        }
    }

    // ---- stable descending sort: 9-round odd-even transposition (36 CEs) ----
    #pragma unroll
    for (int rnd = 0; rnd < 9; ++rnd) {
        if ((rnd & 1) == 0) {
            CE(0, 1); CE(2, 3); CE(4, 5); CE(6, 7);
        } else {
            CE(1, 2); CE(3, 4); CE(5, 6); CE(7, 8);
        }
    }

    // ---- weighted sum over ranks ----
    const float* sp = s + c * 9;
    float acc = 0.0f;
    #pragma unroll
    for (int r = 0; r < 9; ++r)
        acc = fmaf(v[r], sp[r], acc);
    out[gid] = acc;

    // ---- indices: stage in LDS, write back as float4 (coalesced) ----
    // LDS write stride 9 floats/lane: gcd(9,32)=1 -> conflict-free.
    #pragma unroll
    for (int r = 0; r < 9; ++r)
        lds[tid * 9 + r] = id[r];
    __syncthreads();

    // Block's index region: 256*9 = 2304 floats = 576 float4, 16B-aligned
    // (block byte offset = 9216 * blockIdx, divisible by 16).
    float4* dst = (float4*)(idxout + (size_t)blockIdx.x * (BLK * 9));
    const float4* src = (const float4*)lds;
    dst[tid]       = src[tid];
    dst[tid + 256] = src[tid + 256];
    if (tid < 64)
        dst[tid + 512] = src[tid + 512];
}

extern "C" void kernel_launch(void* const* d_in, const int* in_sizes, int n_in,
                              void* d_out, int out_size, void* d_ws, size_t ws_size,
                              hipStream_t stream) {
    const float* x = (const float*)d_in[0];   // [16,128,56,56]
    const float* s = (const float*)d_in[1];   // [128,3,3]
    float* out    = (float*)d_out;            // first NOUT floats
    float* idxout = out + NOUT;               // then NOUT*9 float-encoded ints

    const int nblocks = NOUT / BLK;           // 25088
    rrsvm_kernel<<<nblocks, BLK, 0, stream>>>(x, s, out, idxout);
}

// Round 3
// 279.311 us; speedup vs baseline: 1.0181x; 1.0181x over previous
//
#include <hip/hip_runtime.h>

// RRSVM: per (b,c,h,w) take 3x3 zero-padded window, stable-sort descending,
// out = sum_r v_sorted[r] * s[c,r]; also emit argsort indices (rank order),
// written as float-encoded ints (harness reads whole d_out as float32).
//
// R3 = R2 with compile fix: nontemporal stores need a NATIVE vector type
// (ext_vector_type), not HIP_vector_type<float,4>.
//
// R2 design: 2 pixels/thread (pairs never cross a row since W=56 is even;
// windows share 6/9 taps -> 12 clamped UNCONDITIONAL loads, zeroed by
// cndmask), float2 out store, LDS-staged coalesced nontemporal float4
// index writeback.

#define B_ 16
#define C_ 128
#define H_ 56
#define W_ 56
#define NPIX (B_*C_*H_*W_)   // 6422528
#define BLK 256
#define PXB (BLK * 2)        // 512 pixels per block

typedef float v4f __attribute__((ext_vector_type(4)));

// Stable descending sort: 9-round odd-even transposition, strict adjacent
// compare (equal keys never swap => smaller original index first, matching
// jnp.argsort(-p) stability). Verified absmax==0 in R1.
__device__ __forceinline__ void sort9(float v[9], float id[9]) {
    #pragma unroll
    for (int rnd = 0; rnd < 9; ++rnd) {
        #pragma unroll
        for (int i = (rnd & 1); i + 1 < 9; i += 2) {
            float vi = v[i], vj = v[i + 1];
            float ii = id[i], ij = id[i + 1];
            bool sw = vj > vi;
            v[i]      = sw ? vj : vi;  v[i + 1]  = sw ? vi : vj;
            id[i]     = sw ? ij : ii;  id[i + 1] = sw ? ii : ij;
        }
    }
}

__global__ __launch_bounds__(BLK) void rrsvm_kernel(
    const float* __restrict__ x, const float* __restrict__ s,
    float* __restrict__ out, float* __restrict__ idxout)
{
    __shared__ float lds[PXB * 9];   // 18432 B index staging tile

    const int tid = threadIdx.x;
    const int pix = (blockIdx.x * BLK + tid) * 2;   // even; pair shares a row
    const int w0  = pix % W_;          // even, 0..54; pair is (w0, w0+1)
    const int t   = pix / W_;
    const int h   = t % H_;
    const int bc  = t / H_;            // b*C + c
    const int c   = bc & (C_ - 1);

    // ---- per-channel rank weights (L1/L2 hits, mostly wave-uniform) ----
    const float* sp = s + c * 9;
    float sw9[9];
    #pragma unroll
    for (int r = 0; r < 9; ++r) sw9[r] = sp[r];

    // ---- gather 3 rows x 4 cols, clamped addresses, NO branches ----
    const float* img = x + (size_t)bc * (H_ * W_);
    const int r0 = (h > 0)       ? h - 1  : 0;
    const int r2 = (h < H_ - 1)  ? h + 1  : H_ - 1;
    const int c0 = (w0 > 0)      ? w0 - 1 : 0;
    const int c3 = (w0 < W_ - 2) ? w0 + 2 : W_ - 1;
    const float* p0 = img + r0 * W_;
    const float* p1 = img + h  * W_;
    const float* p2 = img + r2 * W_;

    float tap[3][4];
    tap[0][0] = p0[c0]; tap[0][1] = p0[w0]; tap[0][2] = p0[w0 + 1]; tap[0][3] = p0[c3];
    tap[1][0] = p1[c0]; tap[1][1] = p1[w0]; tap[1][2] = p1[w0 + 1]; tap[1][3] = p1[c3];
    tap[2][0] = p2[c0]; tap[2][1] = p2[w0]; tap[2][2] = p2[w0 + 1]; tap[2][3] = p2[c3];

    const bool rv0 = (h > 0), rv2 = (h < H_ - 1);
    const bool cvL = (w0 > 0), cvR = (w0 < W_ - 2);
    // zero-pad via selects (cndmask), not branches
    tap[0][0] = (rv0 && cvL) ? tap[0][0] : 0.0f;
    tap[0][1] = rv0          ? tap[0][1] : 0.0f;
    tap[0][2] = rv0          ? tap[0][2] : 0.0f;
    tap[0][3] = (rv0 && cvR) ? tap[0][3] : 0.0f;
    tap[1][0] = cvL          ? tap[1][0] : 0.0f;
    tap[1][3] = cvR          ? tap[1][3] : 0.0f;
    tap[2][0] = (rv2 && cvL) ? tap[2][0] : 0.0f;
    tap[2][1] = rv2          ? tap[2][1] : 0.0f;
    tap[2][2] = rv2          ? tap[2][2] : 0.0f;
    tap[2][3] = (rv2 && cvR) ? tap[2][3] : 0.0f;

    float* lbase = lds + tid * 18;   // px0 at +0, px1 at +9
    float2 o;

    // ---- pixel 0: cols 0..2 ----
    {
        float v[9]  = { tap[0][0], tap[0][1], tap[0][2],
                        tap[1][0], tap[1][1], tap[1][2],
                        tap[2][0], tap[2][1], tap[2][2] };
        float id[9] = { 0, 1, 2, 3, 4, 5, 6, 7, 8 };
        sort9(v, id);
        float acc = 0.0f;
        #pragma unroll
        for (int r = 0; r < 9; ++r) acc = fmaf(v[r], sw9[r], acc);
        o.x = acc;
        #pragma unroll
        for (int r = 0; r < 9; ++r) lbase[r] = id[r];
    }
    // ---- pixel 1: cols 1..3 ----
    {
        float v[9]  = { tap[0][1], tap[0][2], tap[0][3],
                        tap[1][1], tap[1][2], tap[1][3],
                        tap[2][1], tap[2][2], tap[2][3] };
        float id[9] = { 0, 1, 2, 3, 4, 5, 6, 7, 8 };
        sort9(v, id);
        float acc = 0.0f;
        #pragma unroll
        for (int r = 0; r < 9; ++r) acc = fmaf(v[r], sw9[r], acc);
        o.y = acc;
        #pragma unroll
        for (int r = 0; r < 9; ++r) lbase[9 + r] = id[r];
    }

    // out store: float2, 8B-aligned (pix even)
    *(float2*)(out + pix) = o;

    __syncthreads();

    // ---- coalesced index writeback: 512*9 = 4608 floats = 1152 float4 ----
    // block byte offset = 18432 * blockIdx (16B aligned). Nontemporal: this
    // 231 MB stream is write-once; keep L2 for x reuse.
    v4f* dst = (v4f*)(idxout + (size_t)blockIdx.x * (PXB * 9));
    const v4f* src = (const v4f*)lds;
    __builtin_nontemporal_store(src[tid],        dst + tid);
    __builtin_nontemporal_store(src[tid + 256],  dst + tid + 256);
    __builtin_nontemporal_store(src[tid + 512],  dst + tid + 512);
    __builtin_nontemporal_store(src[tid + 768],  dst + tid + 768);
    if (tid < 128)
        __builtin_nontemporal_store(src[tid + 1024], dst + tid + 1024);
}

extern "C" void kernel_launch(void* const* d_in, const int* in_sizes, int n_in,
                              void* d_out, int out_size, void* d_ws, size_t ws_size,
                              hipStream_t stream) {
    const float* x = (const float*)d_in[0];   // [16,128,56,56]
    const float* s = (const float*)d_in[1];   // [128,3,3]
    float* out    = (float*)d_out;            // first NPIX floats
    float* idxout = out + NPIX;               // then NPIX*9 float-encoded ints

    const int nblocks = NPIX / PXB;           // 12544
    rrsvm_kernel<<<nblocks, BLK, 0, stream>>>(x, s, out, idxout);
}